// Round 3
// baseline (43.816 us; speedup 1.0000x reference)
//
#include <hip/hip_runtime.h>

typedef __attribute__((ext_vector_type(4))) float  f32x4;
typedef __attribute__((ext_vector_type(8))) short  short8;
typedef __attribute__((ext_vector_type(2))) unsigned int u32x2;

#define NN 200
#define EDIM 128
#define FDIM 16

// ws layout, in shorts (bf16)
#define WS_H      0        // h:       1600*128
#define WS_WNODE  204800   // W_node:  128*128
#define WS_WEDGE  221184   // W_edge:  128*16
#define WS_WWT    223232   // W_weight:128
#define WS_WOUT   223360   // W_out:   128*128
#define WS_TOTAL_CHUNKS 59936   // total f32x4 chunks across the 5 arrays

__device__ __forceinline__ unsigned short f2bf(float f) {
    unsigned u = __float_as_uint(f);
    u += 0x7FFFu + ((u >> 16) & 1u);   // round-to-nearest-even
    return (unsigned short)(u >> 16);
}
__device__ __forceinline__ float bf2f(unsigned short s) {
    return __uint_as_float(((unsigned)s) << 16);
}
__device__ __forceinline__ float tanh_fast(float x) {
    float e = __builtin_amdgcn_exp2f(x * 2.8853900817779268f);  // e^{2x}
    float r = __builtin_amdgcn_rcpf(1.0f + e);
    return __builtin_fmaf(-2.0f, r, 1.0f);
}

// ---- setup: convert h + all weights to bf16 in ws (one pass, ~1MB) ----
__global__ __launch_bounds__(256) void setup_kernel(
    const float* __restrict__ h, const float* __restrict__ W_node,
    const float* __restrict__ W_edge, const float* __restrict__ W_weight,
    const float* __restrict__ W_out, unsigned short* __restrict__ ws)
{
    int c = blockIdx.x * 256 + threadIdx.x;   // f32x4 chunk id
    if (c >= WS_TOTAL_CHUNKS) return;
    const float* src; unsigned short* dst;
    if (c < 51200)      { src = h        + (size_t)c * 4;      dst = ws + WS_H     + c * 4; }
    else if (c < 55296) { src = W_node   + (c - 51200) * 4;    dst = ws + WS_WNODE + (c - 51200) * 4; }
    else if (c < 55808) { src = W_edge   + (c - 55296) * 4;    dst = ws + WS_WEDGE + (c - 55296) * 4; }
    else if (c < 55840) { src = W_weight + (c - 55808) * 4;    dst = ws + WS_WWT   + (c - 55808) * 4; }
    else                { src = W_out    + (c - 55840) * 4;    dst = ws + WS_WOUT  + (c - 55840) * 4; }
    f32x4 v = *(const f32x4*)src;
    u32x2 pk = { (unsigned)f2bf(v.x) | ((unsigned)f2bf(v.y) << 16),
                 (unsigned)f2bf(v.z) | ((unsigned)f2bf(v.w) << 16) };
    *(u32x2*)dst = pk;
}

// ---- fused: one block (256 thr, 4 waves) per (b,n) row ----
// wave w handles m-tiles {w, w+4, w+8, w+12}; A-fragments built directly
// from global (no LDS staging). hi enters msg MFMA as C-input splat.
__global__ __launch_bounds__(256) void fused_kernel(
    const float* __restrict__ ef, const float* __restrict__ Wadj,
    const unsigned short* __restrict__ ws, const float* __restrict__ b_out,
    float* __restrict__ out)
{
    __shared__ float hi_lds[EDIM];
    __shared__ float red[512];

    const int tid  = threadIdx.x;
    const int bn   = blockIdx.x;
    const int lane = tid & 63;
    const int wid  = tid >> 6;      // 0..3
    const int g    = lane >> 4;     // k-group / row-group
    const int l15  = lane & 15;

    const unsigned short* ws_h    = ws + WS_H + bn * EDIM;
    const unsigned short* ws_wn   = ws + WS_WNODE;
    const unsigned short* ws_we   = ws + WS_WEDGE;
    const unsigned short* ws_ww   = ws + WS_WWT;
    const unsigned short* ws_wout = ws + WS_WOUT;

    // ---- hi[e] = sum_k h[k] W_node[e,k] : broadcast-row MFMAs, 2 e-tiles/wave ----
#pragma unroll
    for (int et2 = 0; et2 < 2; ++et2) {
        int et = wid * 2 + et2;
        f32x4 hiacc = {0.f, 0.f, 0.f, 0.f};
#pragma unroll
        for (int s = 0; s < 4; ++s) {
            short8 ah = *(const short8*)(ws_h + s * 32 + g * 8);                     // A[r][k]=h[k]
            short8 bw = *(const short8*)(ws_wn + (et * 16 + l15) * EDIM + s * 32 + g * 8); // B[k][e]=W_node[e][k]
            hiacc = __builtin_amdgcn_mfma_f32_16x16x32_bf16(ah, bw, hiacc, 0, 0, 0);
        }
        if (g == 0) hi_lds[et * 16 + l15] = hiacc[0];   // all D rows equal
    }

    // ---- per-e-tile B fragments for the edge/weight projection (K=32) ----
    short8 bfrag[8];
#pragma unroll
    for (int et = 0; et < 8; ++et) {
        short8 b = {0, 0, 0, 0, 0, 0, 0, 0};
        if (g < 2)        b = *(const short8*)(ws_we + (et * 16 + l15) * FDIM + g * 8);
        else if (g == 2)  b[0] = (short)ws_ww[et * 16 + l15];   // k==16: W_weight[e]
        bfrag[et] = b;
    }

    __syncthreads();
    float hi_e[8];
#pragma unroll
    for (int et = 0; et < 8; ++et) hi_e[et] = hi_lds[et * 16 + l15];

    // ---- m loop: wave-split tiles, A-frag direct from global ----
    float part[8] = {0.f, 0.f, 0.f, 0.f, 0.f, 0.f, 0.f, 0.f};
    for (int mt = wid; mt < 13; mt += 4) {
        int row = mt * 16 + l15;
        if (row > NN - 1) row = NN - 1;          // clamp pad rows (results discarded)
        short8 a = {0, 0, 0, 0, 0, 0, 0, 0};
        if (g < 2) {                              // k 0..15 = ef[row][:]
            const float* p = ef + ((size_t)bn * NN + row) * FDIM + g * 8;
            f32x4 v0 = *(const f32x4*)p;
            f32x4 v1 = *(const f32x4*)(p + 4);
            a[0] = (short)f2bf(v0.x); a[1] = (short)f2bf(v0.y);
            a[2] = (short)f2bf(v0.z); a[3] = (short)f2bf(v0.w);
            a[4] = (short)f2bf(v1.x); a[5] = (short)f2bf(v1.y);
            a[6] = (short)f2bf(v1.z); a[7] = (short)f2bf(v1.w);
        } else if (g == 2) {                      // k==16: W[m]
            a[0] = (short)f2bf(Wadj[bn * NN + row]);
        }
        const bool full = (mt < 12) | (g < 2);    // mt==12: D rows 8..15 are pad
#pragma unroll
        for (int et = 0; et < 8; ++et) {
            f32x4 c = {hi_e[et], hi_e[et], hi_e[et], hi_e[et]};
            c = __builtin_amdgcn_mfma_f32_16x16x32_bf16(a, bfrag[et], c, 0, 0, 0);
            if (full) {
                part[et] += tanh_fast(c[0]);
                part[et] += tanh_fast(c[1]);
                part[et] += tanh_fast(c[2]);
                part[et] += tanh_fast(c[3]);
            }
        }
    }

    // ---- reduce: row-groups within wave, then across waves via LDS ----
#pragma unroll
    for (int et = 0; et < 8; ++et) {
        float p = part[et];
        p += __shfl_xor(p, 16);
        p += __shfl_xor(p, 32);
        part[et] = p;
    }
    if (g == 0) {
#pragma unroll
        for (int et = 0; et < 8; ++et)
            red[wid * EDIM + et * 16 + l15] = part[et];
    }
    __syncthreads();
    if (tid < EDIM)
        hi_lds[tid] = (red[tid] + red[EDIM + tid] + red[2 * EDIM + tid]
                     + red[3 * EDIM + tid]) * (1.0f / (float)NN);   // agg[e]
    __syncthreads();

    // ---- out[f] = sum_e agg[e] W_out[f,e] + b_out[f] (bf16 W_out) ----
    {
        const int f = tid & 127;
        const int c = tid >> 7;                  // e-half
        const unsigned short* wrow = ws_wout + f * EDIM + c * 64;
        const float* arow = hi_lds + c * 64;
        float o = 0.f;
#pragma unroll
        for (int j = 0; j < 64; j += 8) {
            short8 w8 = *(const short8*)(wrow + j);
            f32x4 a0 = *(const f32x4*)(arow + j);
            f32x4 a1 = *(const f32x4*)(arow + j + 4);
            o = __builtin_fmaf(bf2f((unsigned short)w8[0]), a0.x, o);
            o = __builtin_fmaf(bf2f((unsigned short)w8[1]), a0.y, o);
            o = __builtin_fmaf(bf2f((unsigned short)w8[2]), a0.z, o);
            o = __builtin_fmaf(bf2f((unsigned short)w8[3]), a0.w, o);
            o = __builtin_fmaf(bf2f((unsigned short)w8[4]), a1.x, o);
            o = __builtin_fmaf(bf2f((unsigned short)w8[5]), a1.y, o);
            o = __builtin_fmaf(bf2f((unsigned short)w8[6]), a1.z, o);
            o = __builtin_fmaf(bf2f((unsigned short)w8[7]), a1.w, o);
        }
        red[c * 128 + f] = o;
    }
    __syncthreads();
    if (tid < EDIM)
        out[bn * EDIM + tid] = red[tid] + red[128 + tid] + b_out[tid];
}

extern "C" void kernel_launch(void* const* d_in, const int* in_sizes, int n_in,
                              void* d_out, int out_size, void* d_ws, size_t ws_size,
                              hipStream_t stream) {
    const float* h        = (const float*)d_in[0];
    const float* ef       = (const float*)d_in[1];
    const float* W        = (const float*)d_in[2];
    const float* W_node   = (const float*)d_in[3];
    const float* W_edge   = (const float*)d_in[4];
    const float* W_weight = (const float*)d_in[5];
    const float* W_out    = (const float*)d_in[6];
    const float* b_out    = (const float*)d_in[7];
    float* out = (float*)d_out;
    unsigned short* ws = (unsigned short*)d_ws;

    setup_kernel<<<(WS_TOTAL_CHUNKS + 255) / 256, 256, 0, stream>>>(
        h, W_node, W_edge, W_weight, W_out, ws);
    fused_kernel<<<1600, 256, 0, stream>>>(ef, W, ws, b_out, out);
}

// Round 4
// 36.322 us; speedup vs baseline: 1.2063x; 1.2063x over previous
//
#include <hip/hip_runtime.h>

typedef __attribute__((ext_vector_type(4))) float  f32x4;
typedef __attribute__((ext_vector_type(8))) short  short8;
typedef __attribute__((ext_vector_type(2))) unsigned int u32x2;

#define NN 200
#define EDIM 128
#define FDIM 16
#define BN_TOTAL 1600
#define NCHUNK 7            // m-chunks of 32 rows (chunk 6: rows 192..199 valid)

// ws layout: bf16 region (short index), then f32 region (float index)
#define WS_WE    0          // W_edge  bf16 [128][16]
#define WS_WWT   2048       // W_weight bf16 [128]
#define WS_WOUT  2176       // W_out   bf16 [128][128]
#define WSF_HI    10240     // hi      f32 [1600][128]   (byte 40960)
#define WSF_PART  215040    // partial f32 [7][1600][128] (byte 860160)

__device__ __forceinline__ unsigned short f2bf(float f) {
    unsigned u = __float_as_uint(f);
    u += 0x7FFFu + ((u >> 16) & 1u);   // RNE
    return (unsigned short)(u >> 16);
}
__device__ __forceinline__ short8 cvt8(f32x4 a, f32x4 b) {
    short8 r;
    r[0]=(short)f2bf(a.x); r[1]=(short)f2bf(a.y); r[2]=(short)f2bf(a.z); r[3]=(short)f2bf(a.w);
    r[4]=(short)f2bf(b.x); r[5]=(short)f2bf(b.y); r[6]=(short)f2bf(b.z); r[7]=(short)f2bf(b.w);
    return r;
}
__device__ __forceinline__ float tanh_fast(float x) {
    float e = __builtin_amdgcn_exp2f(x * 2.8853900817779268f);  // e^{2x}
    float r = __builtin_amdgcn_rcpf(1.0f + e);
    return __builtin_fmaf(-2.0f, r, 1.0f);
}

// ---------------------------------------------------------------------------
// setup: blocks 0..99  -> hi GEMM (M-tile of 16 bn-rows each, 2 waves x 4 et)
//        blocks 100..107 -> bf16 conversion of W_edge / W_weight / W_out
// ---------------------------------------------------------------------------
__global__ __launch_bounds__(128) void setup_kernel(
    const float* __restrict__ h, const float* __restrict__ W_node,
    const float* __restrict__ W_edge, const float* __restrict__ W_weight,
    const float* __restrict__ W_out, void* __restrict__ wsv)
{
    unsigned short* wsb = (unsigned short*)wsv;
    float* wsf = (float*)wsv;
    const int blk = blockIdx.x;
    const int tid = threadIdx.x;

    if (blk < 100) {
        const int lane = tid & 63;
        const int w    = tid >> 6;        // 0..1 -> et half
        const int g    = lane >> 4;
        const int l15  = lane & 15;
        const int r0   = blk * 16;

        short8 afr[4];
#pragma unroll
        for (int ks = 0; ks < 4; ++ks) {
            const float* p = h + (size_t)(r0 + l15) * EDIM + ks * 32 + g * 8;
            afr[ks] = cvt8(*(const f32x4*)p, *(const f32x4*)(p + 4));
        }
#pragma unroll
        for (int e2 = 0; e2 < 4; ++e2) {
            const int et = w * 4 + e2;
            f32x4 acc = {0.f, 0.f, 0.f, 0.f};
#pragma unroll
            for (int ks = 0; ks < 4; ++ks) {
                const float* p = W_node + (size_t)(et * 16 + l15) * EDIM + ks * 32 + g * 8;
                short8 bfr = cvt8(*(const f32x4*)p, *(const f32x4*)(p + 4));
                acc = __builtin_amdgcn_mfma_f32_16x16x32_bf16(afr[ks], bfr, acc, 0, 0, 0);
            }
#pragma unroll
            for (int r = 0; r < 4; ++r)
                wsf[WSF_HI + (size_t)(r0 + g * 4 + r) * EDIM + et * 16 + l15] = acc[r];
        }
    } else {
        // 4640 f32x4 chunks: [0,512) W_edge, [512,544) W_weight, [544,4640) W_out
        for (int c = (blk - 100) * 128 + tid; c < 4640; c += 8 * 128) {
            const float* src; unsigned short* dst;
            if (c < 512)      { src = W_edge   + c * 4;         dst = wsb + WS_WE   + c * 4; }
            else if (c < 544) { src = W_weight + (c - 512) * 4; dst = wsb + WS_WWT  + (c - 512) * 4; }
            else              { src = W_out    + (c - 544) * 4; dst = wsb + WS_WOUT + (c - 544) * 4; }
            f32x4 v = *(const f32x4*)src;
            u32x2 pk = { (unsigned)f2bf(v.x) | ((unsigned)f2bf(v.y) << 16),
                         (unsigned)f2bf(v.z) | ((unsigned)f2bf(v.w) << 16) };
            *(u32x2*)dst = pk;
        }
    }
}

// ---------------------------------------------------------------------------
// msg: one WAVE per (bn, m-chunk of 32 rows). No LDS, no barriers, no
// runtime loops. Writes per-chunk partial sums to ws.
// ---------------------------------------------------------------------------
__global__ __launch_bounds__(64) void msg_kernel(
    const float* __restrict__ ef, const float* __restrict__ Wadj,
    void* __restrict__ wsv)
{
    const unsigned short* wsb = (const unsigned short*)wsv;
    const float* wsf = (const float*)wsv;
    float* wsp = (float*)wsv;

    const int blk  = blockIdx.x;
    const int bn   = blk / NCHUNK;
    const int cj   = blk - bn * NCHUNK;
    const int lane = threadIdx.x;
    const int g    = lane >> 4;
    const int l15  = lane & 15;
    const int m0   = cj * 32;

    // hi[e] for this lane's 8 e-columns (broadcast across g)
    float hi_e[8];
#pragma unroll
    for (int et = 0; et < 8; ++et)
        hi_e[et] = wsf[WSF_HI + (size_t)bn * EDIM + et * 16 + l15];

    // B fragments (K=32: 16 ef + W-channel at k=16 + zero pad)
    short8 bfrag[8];
#pragma unroll
    for (int et = 0; et < 8; ++et) {
        short8 b = {0, 0, 0, 0, 0, 0, 0, 0};
        if (g < 2)       b = *(const short8*)(wsb + WS_WE + (et * 16 + l15) * FDIM + g * 8);
        else if (g == 2) b[0] = (short)wsb[WS_WWT + et * 16 + l15];
        bfrag[et] = b;
    }

    // A fragment, tile 0 (rows m0..m0+15; chunk 6: rows 200..207 clamped/dead)
    short8 a0 = {0, 0, 0, 0, 0, 0, 0, 0};
    {
        int row = m0 + l15; if (row > NN - 1) row = NN - 1;
        if (g < 2) {
            const float* p = ef + ((size_t)bn * NN + row) * FDIM + g * 8;
            a0 = cvt8(*(const f32x4*)p, *(const f32x4*)(p + 4));
        } else if (g == 2) {
            a0[0] = (short)f2bf(Wadj[bn * NN + row]);
        }
    }
    // A fragment, tile 1 (rows m0+16..m0+31; absent for chunk 6)
    short8 a1 = {0, 0, 0, 0, 0, 0, 0, 0};
    const bool has1 = (cj < 6);
    if (has1) {
        int row = m0 + 16 + l15;          // always < 200 when cj<6
        if (g < 2) {
            const float* p = ef + ((size_t)bn * NN + row) * FDIM + g * 8;
            a1 = cvt8(*(const f32x4*)p, *(const f32x4*)(p + 4));
        } else if (g == 2) {
            a1[0] = (short)f2bf(Wadj[bn * NN + row]);
        }
    }

    const bool full0 = (cj < 6) | (g < 2);   // chunk 6: C rows g*4+r valid iff g<2
    float part[8];
#pragma unroll
    for (int et = 0; et < 8; ++et) part[et] = 0.f;

#pragma unroll
    for (int et = 0; et < 8; ++et) {
        f32x4 c0 = {hi_e[et], hi_e[et], hi_e[et], hi_e[et]};
        c0 = __builtin_amdgcn_mfma_f32_16x16x32_bf16(a0, bfrag[et], c0, 0, 0, 0);
        if (full0)
            part[et] += tanh_fast(c0[0]) + tanh_fast(c0[1])
                      + tanh_fast(c0[2]) + tanh_fast(c0[3]);
    }
    if (has1) {
#pragma unroll
        for (int et = 0; et < 8; ++et) {
            f32x4 c1 = {hi_e[et], hi_e[et], hi_e[et], hi_e[et]};
            c1 = __builtin_amdgcn_mfma_f32_16x16x32_bf16(a1, bfrag[et], c1, 0, 0, 0);
            part[et] += tanh_fast(c1[0]) + tanh_fast(c1[1])
                      + tanh_fast(c1[2]) + tanh_fast(c1[3]);
        }
    }

    // reduce across g-groups, store partial (lanes 0..15 per et)
#pragma unroll
    for (int et = 0; et < 8; ++et) {
        float p = part[et];
        p += __shfl_xor(p, 16);
        p += __shfl_xor(p, 32);
        if (g == 0)
            wsp[WSF_PART + ((size_t)cj * BN_TOTAL + bn) * EDIM + et * 16 + l15] = p;
    }
}

// ---------------------------------------------------------------------------
// outproj: 100 blocks x 128 thr. Block = 16 bn-rows; wave = 4 f-tiles.
// A = bf16( (sum of 7 partials) / 200 ), B = bf16 W_out (pre-converted).
// ---------------------------------------------------------------------------
__global__ __launch_bounds__(128) void outproj_kernel(
    const void* __restrict__ wsv, const float* __restrict__ b_out,
    float* __restrict__ out)
{
    const unsigned short* wsb = (const unsigned short*)wsv;
    const float* wsf = (const float*)wsv;
    const int tid  = threadIdx.x;
    const int lane = tid & 63;
    const int w    = tid >> 6;
    const int g    = lane >> 4;
    const int l15  = lane & 15;
    const int r0   = blockIdx.x * 16;

    short8 afr[4];
#pragma unroll
    for (int ks = 0; ks < 4; ++ks) {
        const size_t off = (size_t)(r0 + l15) * EDIM + ks * 32 + g * 8;
        f32x4 s0 = {0.f, 0.f, 0.f, 0.f}, s1 = {0.f, 0.f, 0.f, 0.f};
#pragma unroll
        for (int j = 0; j < NCHUNK; ++j) {
            const float* p = wsf + WSF_PART + (size_t)j * (BN_TOTAL * EDIM) + off;
            s0 += *(const f32x4*)p;
            s1 += *(const f32x4*)(p + 4);
        }
        const float sc = 1.0f / (float)NN;
        afr[ks] = cvt8(s0 * sc, s1 * sc);
    }
#pragma unroll
    for (int f2 = 0; f2 < 4; ++f2) {
        const int ft = w * 4 + f2;
        f32x4 acc = {0.f, 0.f, 0.f, 0.f};
#pragma unroll
        for (int ks = 0; ks < 4; ++ks) {
            short8 b = *(const short8*)(wsb + WS_WOUT + (ft * 16 + l15) * EDIM + ks * 32 + g * 8);
            acc = __builtin_amdgcn_mfma_f32_16x16x32_bf16(afr[ks], b, acc, 0, 0, 0);
        }
        const float bo = b_out[ft * 16 + l15];
#pragma unroll
        for (int r = 0; r < 4; ++r)
            out[(size_t)(r0 + g * 4 + r) * EDIM + ft * 16 + l15] = acc[r] + bo;
    }
}

extern "C" void kernel_launch(void* const* d_in, const int* in_sizes, int n_in,
                              void* d_out, int out_size, void* d_ws, size_t ws_size,
                              hipStream_t stream) {
    const float* h        = (const float*)d_in[0];
    const float* ef       = (const float*)d_in[1];
    const float* W        = (const float*)d_in[2];
    const float* W_node   = (const float*)d_in[3];
    const float* W_edge   = (const float*)d_in[4];
    const float* W_weight = (const float*)d_in[5];
    const float* W_out    = (const float*)d_in[6];
    const float* b_out    = (const float*)d_in[7];
    float* out = (float*)d_out;

    setup_kernel<<<108, 128, 0, stream>>>(h, W_node, W_edge, W_weight, W_out, d_ws);
    msg_kernel<<<BN_TOTAL * NCHUNK, 64, 0, stream>>>(ef, W, d_ws);
    outproj_kernel<<<100, 128, 0, stream>>>(d_ws, b_out, out);
}